// Round 7
// baseline (34.187 us; speedup 1.0000x reference)
//
#include <hip/hip_runtime.h>

// Problem constants (fixed by the reference file): B=8, N=4096.
#define NN 4096
#define BB 8
#define JT 4      // ISNet rows (j) per block
#define CK 1024   // k per LDS chunk
#define NC (NN / CK)  // 4 chunks

// Grid: NN/JT = 1024 blocks x 256 threads (4 waves).
// Block owns rows j0..j0+3; wave w owns batches {2w,2w+1} over all k.
// w rows are staged through LDS once per block (wave w reg-stages row w,
// chunked, double-buffered) -> removes the 4x redundant global w traffic
// that bound rounds 4/6. I rows stay global (disjoint per wave, L2-resident).
// Math identical to the round-4/6 pass: z = (S*p01*w)*I in f32, 4 factors
// combine exactly-in-f32 (pairwise fmaf) to one q, running product in f64.

__device__ __forceinline__ float2 pk_mul(float2 a, float2 b) {
    return make_float2(a.x * b.x, a.y * b.y);
}
__device__ __forceinline__ float2 pk_add(float2 a, float2 b) {
    return make_float2(a.x + b.x, a.y + b.y);
}
__device__ __forceinline__ float2 pk_fnma(float2 a, float2 b, float2 c) {  // c - a*b
    return make_float2(fmaf(-a.x, b.x, c.x), fmaf(-a.y, b.y, c.y));
}

__global__ __launch_bounds__(256, 4) void epi_kernel(
    const float* __restrict__ state,    // [B,4,N]
    const float* __restrict__ ISNet,    // [N,N]
    const float* __restrict__ psMatrix, // [4,4]
    const float* __restrict__ U,        // [N]
    float* __restrict__ out)            // [B,4,N]
{
    const int j0   = blockIdx.x * JT;
    const int tid  = threadIdx.x;
    const int wave = tid >> 6;
    const int lane = tid & 63;
    const int b0   = wave * 2;          // this wave's two batches

    __shared__ float  wlds[2][JT][CK];  // 32 KB double-buffered w tile
    __shared__ double red[JT][BB];

    const float p01 = psMatrix[1];      // psM[0,1] == psMatrix[0,1]

    float  cf[JT][2];
    double prod[JT][2];
    #pragma unroll
    for (int jj = 0; jj < JT; ++jj) {
        #pragma unroll
        for (int bi = 0; bi < 2; ++bi) {
            cf[jj][bi]   = state[(size_t)(b0 + bi) * 4 * NN + (j0 + jj)] * p01;
            prod[jj][bi] = 1.0;
        }
    }

    // Wave w stages ISNet row (j0 + w): per chunk, 4 float4 per lane.
    const float* __restrict__ wrow = ISNet + (size_t)(j0 + wave) * NN;
    const float4* __restrict__ i0  = (const float4*)(state + ((size_t)(b0 + 0) * 4 + 2) * NN);
    const float4* __restrict__ i1  = (const float4*)(state + ((size_t)(b0 + 1) * 4 + 2) * NN);

    float4 stg[4];

#define LOAD_STAGE(C)                                               \
    do {                                                            \
        const float4* _src = (const float4*)(wrow + (C) * CK);      \
        _Pragma("unroll")                                           \
        for (int g = 0; g < 4; ++g) stg[g] = _src[g * 64 + lane];   \
    } while (0)
#define WRITE_STAGE(BUF)                                            \
    do {                                                            \
        _Pragma("unroll")                                           \
        for (int g = 0; g < 4; ++g)                                 \
            *((float4*)&wlds[BUF][wave][(g * 64 + lane) * 4]) = stg[g]; \
    } while (0)

    auto compute = [&](const float4 (&W)[JT], const float4& I0, const float4& I1) {
        #pragma unroll
        for (int jj = 0; jj < JT; ++jj) {
            const float2 w01 = make_float2(W[jj].x, W[jj].y);
            const float2 w23 = make_float2(W[jj].z, W[jj].w);
            #pragma unroll
            for (int bi = 0; bi < 2; ++bi) {
                const float4& I  = bi ? I1 : I0;
                const float2 c2  = make_float2(cf[jj][bi], cf[jj][bi]);
                const float2 i01 = make_float2(I.x, I.y);
                const float2 i23 = make_float2(I.z, I.w);
                const float2 z01 = pk_mul(pk_mul(c2, w01), i01);
                const float2 z23 = pk_mul(pk_mul(c2, w23), i23);
                const float2 q2  = pk_fnma(z01, z23, pk_add(z01, z23));
                const float  q   = fmaf(-q2.x, q2.y, q2.x + q2.y);
                prod[jj][bi] = fma(-(double)q, prod[jj][bi], prod[jj][bi]);
            }
        }
    };

    // Pipeline: stage chunk 0, pre-issue chunk 1's loads; inside chunk c the
    // loads for chunk c+2 are issued so each __syncthreads' vmcnt-drain only
    // meets loads that have had a full chunk of compute to complete.
    LOAD_STAGE(0);
    WRITE_STAGE(0);
    LOAD_STAGE(1);

    for (int c = 0; c < NC; ++c) {
        __syncthreads();                       // wlds[c&1] visible to all waves
        if (c + 1 < NC) WRITE_STAGE((c + 1) & 1);
        if (c + 2 < NC) LOAD_STAGE(c + 2);

        // This chunk's I values (disjoint per wave, L2-resident).
        float4 iv0[4], iv1[4];
        #pragma unroll
        for (int g = 0; g < 4; ++g) {
            const int x = (c * CK / 4) + g * 64 + lane;
            iv0[g] = i0[x];
            iv1[g] = i1[x];
        }

        #pragma unroll
        for (int it = 0; it < 4; ++it) {
            float4 wv[JT];
            #pragma unroll
            for (int jj = 0; jj < JT; ++jj)
                wv[jj] = *((const float4*)&wlds[c & 1][jj][(it * 64 + lane) * 4]);
            compute(wv, iv0[it], iv1[it]);
        }
    }
#undef LOAD_STAGE
#undef WRITE_STAGE

    // 3 XOR-butterfly levels: every lane holds the partial product over its
    // residue class {m : m ≡ lane (mod 8)}.
    #pragma unroll
    for (int off = 32; off >= 8; off >>= 1) {
        #pragma unroll
        for (int jj = 0; jj < JT; ++jj) {
            #pragma unroll
            for (int bi = 0; bi < 2; ++bi)
                prod[jj][bi] *= __shfl_xor(prod[jj][bi], off, 64);
        }
    }

    // 8-lane group g reduces pair g: its lanes cover all 8 residues.
    const int g = lane >> 3;
    double v = prod[0][0];
    v = (g == 1) ? prod[0][1] : v;
    v = (g == 2) ? prod[1][0] : v;
    v = (g == 3) ? prod[1][1] : v;
    v = (g == 4) ? prod[2][0] : v;
    v = (g == 5) ? prod[2][1] : v;
    v = (g == 6) ? prod[3][0] : v;
    v = (g == 7) ? prod[3][1] : v;
    v *= __shfl_down(v, 4, 64);
    v *= __shfl_down(v, 2, 64);
    v *= __shfl_down(v, 1, 64);

    if ((lane & 7) == 0)               // pair g = (jj<<1)|bi
        red[g >> 1][b0 + (g & 1)] = v;
    __syncthreads();

    if (tid < JT * BB) {   // 32 threads: (jj, b)
        const int jj = tid >> 3, b = tid & 7;
        const int j  = j0 + jj;
        const double tot = red[jj][b];
        const double ps1 = 1.0 - tot;

        // expand_psMatrix in f64
        double pm[4][4];
        #pragma unroll
        for (int r = 0; r < 4; ++r) {
            double s = 0.0;
            #pragma unroll
            for (int q = 0; q < 4; ++q) {
                pm[r][q] = (double)psMatrix[r * 4 + q];
                s += pm[r][q];
            }
            pm[r][r] += (1.0 - s);
        }

        double st[4];
        #pragma unroll
        for (int r = 0; r < 4; ++r)
            st[r] = (double)state[(size_t)b * 4 * NN + r * NN + j];

        const double S = st[0];
        const double ps10[4] = {1.0 - ps1, ps1, 0.0, 0.0};

        double P[4];
        #pragma unroll
        for (int i = 0; i < 4; ++i) {
            double acc = S * ps10[i];
            #pragma unroll
            for (int r = 1; r < 4; ++r)
                acc += pm[r][i] * st[r];
            P[i] = acc;
        }

        double u = (double)U[j];
        #pragma unroll
        for (int i = 0; i < 4; ++i) {
            u -= P[i];
            const double s = (u < 0.0) ? 1.0 : 0.0;
            out[(size_t)b * 4 * NN + i * NN + j] = (float)s;
            u += s;
        }
    }
}

extern "C" void kernel_launch(void* const* d_in, const int* in_sizes, int n_in,
                              void* d_out, int out_size, void* d_ws, size_t ws_size,
                              hipStream_t stream) {
    const float* state    = (const float*)d_in[0];  // [8,4,4096]
    const float* ISNet    = (const float*)d_in[1];  // [4096,4096]
    const float* psMatrix = (const float*)d_in[2];  // [4,4]
    const float* U        = (const float*)d_in[3];  // [4096]
    float* out            = (float*)d_out;          // [8,4,4096]

    epi_kernel<<<NN / JT, 256, 0, stream>>>(state, ISNet, psMatrix, U, out);
}

// Round 8
// 33.318 us; speedup vs baseline: 1.0261x; 1.0261x over previous
//
#include <hip/hip_runtime.h>

// Problem constants (fixed by the reference file): B=8, N=4096.
#define NN 4096
#define BB 8
#define JT 4          // ISNet rows per block = waves per block
#define CK 1024       // k per LDS chunk
#define NC (NN / CK)  // 4 chunks

// Grid: NN/JT = 1024 blocks x 256 threads (4 waves).
// Wave w owns row j = j0 + w for ALL 8 batches over all k  -> each w-row is
// read from global exactly once per block (kills the 4x L3 w-redundancy that
// bound rounds 4/6 at ~10.7 TB/s).
// I = state[:,2,:] (8 rows) is staged through LDS in k-chunks of 1024
// (2 x 32 KB double buffer). T14 split: global I-loads issued right after the
// barrier, ds_writes after the chunk's compute -> no vmcnt stall at the
// barrier, no registers spilled across it (round-7 bug: 35 MB scratch).
// Math identical to the round-4/6 pass: z = (S*p01*w)*I in f32, 4 factors
// combine exactly-in-f32 (pairwise fmaf) to one q, running product in f64.
// Each wave reduces its own 8 products (3 xor + select + 3 down) and its
// lanes 8g run the epilogue for batch g -> no cross-wave combine, no LDS red.

__device__ __forceinline__ float2 pk_mul(float2 a, float2 b) {
    return make_float2(a.x * b.x, a.y * b.y);
}
__device__ __forceinline__ float2 pk_add(float2 a, float2 b) {
    return make_float2(a.x + b.x, a.y + b.y);
}
__device__ __forceinline__ float2 pk_fnma(float2 a, float2 b, float2 c) {  // c - a*b
    return make_float2(fmaf(-a.x, b.x, c.x), fmaf(-a.y, b.y, c.y));
}

__global__ __launch_bounds__(256, 2) void epi_kernel(
    const float* __restrict__ state,    // [B,4,N]
    const float* __restrict__ ISNet,    // [N,N]
    const float* __restrict__ psMatrix, // [4,4]
    const float* __restrict__ U,        // [N]
    float* __restrict__ out)            // [B,4,N]
{
    const int j0   = blockIdx.x * JT;
    const int tid  = threadIdx.x;
    const int wave = tid >> 6;
    const int lane = tid & 63;
    const int j    = j0 + wave;         // this wave's ISNet row

    __shared__ float ilds[2][BB][CK];   // 64 KB double-buffered I tile

    const float p01 = psMatrix[1];      // psM[0,1] == psMatrix[0,1]

    float  cf[BB];
    double prod[BB];
    #pragma unroll
    for (int b = 0; b < BB; ++b) {
        cf[b]   = state[(size_t)b * 4 * NN + j] * p01;  // S[b,j]*p01
        prod[b] = 1.0;
    }

    const float4* __restrict__ wrow4 = (const float4*)(ISNet + (size_t)j * NN);

    // I staging: thread t covers batch-row sr = t>>5, float4 slots sc+32q.
    const int sr = tid >> 5;            // 0..7
    const int sc = tid & 31;
    const float4* __restrict__ isrc = (const float4*)(state + ((size_t)sr * 4 + 2) * NN);

    float4 sreg[8];                     // staging regs (32 KB chunk / 256 thr)
    float4 wcur[4], wnxt[4];            // this wave's w row, chunk-sized

    // Prologue: chunk 0 -> regs -> LDS; w chunk 0 -> regs.
    #pragma unroll
    for (int q = 0; q < 8; ++q) sreg[q] = isrc[sc + 32 * q];
    #pragma unroll
    for (int g = 0; g < 4; ++g) wcur[g] = wrow4[g * 64 + lane];
    #pragma unroll
    for (int q = 0; q < 8; ++q)
        *((float4*)&ilds[0][sr][(sc + 32 * q) * 4]) = sreg[q];

    for (int c = 0; c < NC; ++c) {
        __syncthreads();                // ilds[c&1] visible to all waves

        // Early-issue next chunk's global loads (consumed after compute).
        if (c + 1 < NC) {
            const int base = (c + 1) * (CK / 4);
            #pragma unroll
            for (int q = 0; q < 8; ++q) sreg[q] = isrc[base + sc + 32 * q];
            #pragma unroll
            for (int g = 0; g < 4; ++g) wnxt[g] = wrow4[base + g * 64 + lane];
        }

        // Compute chunk c: 4 float4-stages per lane.
        #pragma unroll
        for (int it = 0; it < 4; ++it) {
            const float4 wv  = wcur[it];
            const float2 w01 = make_float2(wv.x, wv.y);
            const float2 w23 = make_float2(wv.z, wv.w);
            #pragma unroll
            for (int b = 0; b < BB; ++b) {
                const float4 I = *((const float4*)&ilds[c & 1][b][(it * 64 + lane) * 4]);
                const float2 c2  = make_float2(cf[b], cf[b]);
                const float2 z01 = pk_mul(pk_mul(c2, w01), make_float2(I.x, I.y));
                const float2 z23 = pk_mul(pk_mul(c2, w23), make_float2(I.z, I.w));
                const float2 q2  = pk_fnma(z01, z23, pk_add(z01, z23));
                const float  q   = fmaf(-q2.x, q2.y, q2.x + q2.y);
                prod[b] = fma(-(double)q, prod[b], prod[b]);
            }
        }

        // Late ds_writes for chunk c+1 (loads have had the whole compute
        // phase to land); rotate w buffers.
        if (c + 1 < NC) {
            #pragma unroll
            for (int q = 0; q < 8; ++q)
                *((float4*)&ilds[(c + 1) & 1][sr][(sc + 32 * q) * 4]) = sreg[q];
            #pragma unroll
            for (int g = 0; g < 4; ++g) wcur[g] = wnxt[g];
        }
    }

    // 3 XOR-butterfly levels: every lane holds the partial product over its
    // residue class {m : m ≡ lane (mod 8)}.
    #pragma unroll
    for (int off = 32; off >= 8; off >>= 1) {
        #pragma unroll
        for (int b = 0; b < BB; ++b)
            prod[b] *= __shfl_xor(prod[b], off, 64);
    }

    // 8-lane group g reduces batch g; lane 8g ends with the full product.
    const int g = lane >> 3;
    double v = prod[0];
    #pragma unroll
    for (int b = 1; b < BB; ++b) v = (g == b) ? prod[b] : v;
    v *= __shfl_down(v, 4, 64);
    v *= __shfl_down(v, 2, 64);
    v *= __shfl_down(v, 1, 64);

    if ((lane & 7) == 0) {              // 8 active lanes: batch g, row j
        const int b = g;
        const double ps1 = 1.0 - v;

        // expand_psMatrix in f64
        double pm[4][4];
        #pragma unroll
        for (int r = 0; r < 4; ++r) {
            double s = 0.0;
            #pragma unroll
            for (int q = 0; q < 4; ++q) {
                pm[r][q] = (double)psMatrix[r * 4 + q];
                s += pm[r][q];
            }
            pm[r][r] += (1.0 - s);
        }

        double st[4];
        #pragma unroll
        for (int r = 0; r < 4; ++r)
            st[r] = (double)state[(size_t)b * 4 * NN + r * NN + j];

        const double S = st[0];
        const double ps10[4] = {1.0 - ps1, ps1, 0.0, 0.0};

        double P[4];
        #pragma unroll
        for (int i = 0; i < 4; ++i) {
            double acc = S * ps10[i];
            #pragma unroll
            for (int r = 1; r < 4; ++r)
                acc += pm[r][i] * st[r];
            P[i] = acc;
        }

        double u = (double)U[j];
        #pragma unroll
        for (int i = 0; i < 4; ++i) {
            u -= P[i];
            const double s = (u < 0.0) ? 1.0 : 0.0;
            out[(size_t)b * 4 * NN + i * NN + j] = (float)s;
            u += s;
        }
    }
}

extern "C" void kernel_launch(void* const* d_in, const int* in_sizes, int n_in,
                              void* d_out, int out_size, void* d_ws, size_t ws_size,
                              hipStream_t stream) {
    const float* state    = (const float*)d_in[0];  // [8,4,4096]
    const float* ISNet    = (const float*)d_in[1];  // [4096,4096]
    const float* psMatrix = (const float*)d_in[2];  // [4,4]
    const float* U        = (const float*)d_in[3];  // [4096]
    float* out            = (float*)d_out;          // [8,4,4096]

    epi_kernel<<<NN / JT, 256, 0, stream>>>(state, ISNet, psMatrix, U, out);
}

// Round 9
// 28.651 us; speedup vs baseline: 1.1933x; 1.1629x over previous
//
#include <hip/hip_runtime.h>

// Problem constants (fixed by the reference file): B=8, N=4096.
#define NN 4096
#define BB 8
#define JT 4          // ISNet rows per block = waves per block
#define KS 2          // k-splits
#define KH (NN / KS)  // 2048 k per block
#define CK 512        // k per LDS chunk
#define NC (KH / CK)  // 4 chunks

// Main kernel, grid = (NN/JT)*KS = 2048 blocks x 256 threads (4 waves).
// Block (jb, ks): rows j0..j0+3, k in [ks*KH, (ks+1)*KH).
// Wave w owns row j0+w for ALL 8 batches over the k-half -> each w element
// read from global exactly once chip-wide (64 MB); I staged through LDS once
// per block (128 MB chip-wide). LDS = 2 x 16 KB double buffer (32 KB -> 5
// blocks/CU residency; round-8's 64 KB capped at 2 and starved TLP).
// Partial f64 products -> d_ws; combine kernel multiplies the two k-halves
// and runs the (4x4 mix + cumulative-threshold sampling) epilogue, coalesced.
// Factor math identical to the round-4/6/8 passing scheme.

__device__ __forceinline__ float2 pk_mul(float2 a, float2 b) {
    return make_float2(a.x * b.x, a.y * b.y);
}
__device__ __forceinline__ float2 pk_add(float2 a, float2 b) {
    return make_float2(a.x + b.x, a.y + b.y);
}
__device__ __forceinline__ float2 pk_fnma(float2 a, float2 b, float2 c) {  // c - a*b
    return make_float2(fmaf(-a.x, b.x, c.x), fmaf(-a.y, b.y, c.y));
}

__global__ __launch_bounds__(256, 5) void epi_partial(
    const float* __restrict__ state,    // [B,4,N]
    const float* __restrict__ ISNet,    // [N,N]
    const float* __restrict__ psMatrix, // [4,4]
    double* __restrict__ ws)            // [KS,BB,NN] partial products
{
    const int ks   = blockIdx.x & (KS - 1);
    const int jb   = blockIdx.x >> 1;
    const int j0   = jb * JT;
    const int tid  = threadIdx.x;
    const int wave = tid >> 6;
    const int lane = tid & 63;
    const int j    = j0 + wave;          // this wave's ISNet row
    const int kb   = ks * KH;            // k-half base

    __shared__ float ilds[2][BB][CK];    // 32 KB double-buffered I tile

    const float p01 = psMatrix[1];       // psM[0,1] == psMatrix[0,1]

    float  cf[BB];
    double prod[BB];
    #pragma unroll
    for (int b = 0; b < BB; ++b) {
        cf[b]   = state[(size_t)b * 4 * NN + j] * p01;  // S[b,j]*p01
        prod[b] = 1.0;
    }

    const float4* __restrict__ wrow4 = (const float4*)(ISNet + (size_t)j * NN + kb);

    // I staging: thread t covers batch-row sr = t>>5, float4 slots sc+32q.
    const int sr = tid >> 5;             // 0..7
    const int sc = tid & 31;             // 0..31
    const float4* __restrict__ isrc =
        (const float4*)(state + ((size_t)sr * 4 + 2) * NN + kb);

    float4 sreg[4];                      // 16 KB chunk / 256 threads
    float4 wcur[2], wnxt[2];             // this wave's w row, chunk-sized

    // Prologue: chunk 0 -> regs -> LDS; w chunk 0 -> regs.
    #pragma unroll
    for (int q = 0; q < 4; ++q) sreg[q] = isrc[sc + 32 * q];
    #pragma unroll
    for (int g = 0; g < 2; ++g) wcur[g] = wrow4[g * 64 + lane];
    #pragma unroll
    for (int q = 0; q < 4; ++q)
        *((float4*)&ilds[0][sr][(sc + 32 * q) * 4]) = sreg[q];

    for (int c = 0; c < NC; ++c) {
        __syncthreads();                 // ilds[c&1] visible to all waves

        // Early-issue next chunk's global loads (consumed after compute).
        if (c + 1 < NC) {
            const int base = (c + 1) * (CK / 4);
            #pragma unroll
            for (int q = 0; q < 4; ++q) sreg[q] = isrc[base + sc + 32 * q];
            #pragma unroll
            for (int g = 0; g < 2; ++g) wnxt[g] = wrow4[base + g * 64 + lane];
        }

        // Compute chunk c: 2 float4-stages per lane.
        #pragma unroll
        for (int it = 0; it < 2; ++it) {
            const float4 wv  = wcur[it];
            const float2 w01 = make_float2(wv.x, wv.y);
            const float2 w23 = make_float2(wv.z, wv.w);
            #pragma unroll
            for (int b = 0; b < BB; ++b) {
                const float4 I = *((const float4*)&ilds[c & 1][b][(it * 64 + lane) * 4]);
                const float2 c2  = make_float2(cf[b], cf[b]);
                const float2 z01 = pk_mul(pk_mul(c2, w01), make_float2(I.x, I.y));
                const float2 z23 = pk_mul(pk_mul(c2, w23), make_float2(I.z, I.w));
                const float2 q2  = pk_fnma(z01, z23, pk_add(z01, z23));
                const float  q   = fmaf(-q2.x, q2.y, q2.x + q2.y);
                prod[b] = fma(-(double)q, prod[b], prod[b]);
            }
        }

        // Late ds_writes for chunk c+1; rotate w buffers.
        if (c + 1 < NC) {
            #pragma unroll
            for (int q = 0; q < 4; ++q)
                *((float4*)&ilds[(c + 1) & 1][sr][(sc + 32 * q) * 4]) = sreg[q];
            wcur[0] = wnxt[0];
            wcur[1] = wnxt[1];
        }
    }

    // 3 XOR-butterfly levels: every lane holds the partial over its mod-8
    // residue class; group g then reduces batch g with 3 down-levels.
    #pragma unroll
    for (int off = 32; off >= 8; off >>= 1) {
        #pragma unroll
        for (int b = 0; b < BB; ++b)
            prod[b] *= __shfl_xor(prod[b], off, 64);
    }
    const int g = lane >> 3;
    double v = prod[0];
    #pragma unroll
    for (int b = 1; b < BB; ++b) v = (g == b) ? prod[b] : v;
    v *= __shfl_down(v, 4, 64);
    v *= __shfl_down(v, 2, 64);
    v *= __shfl_down(v, 1, 64);

    if ((lane & 7) == 0)                 // batch g, row j, half ks
        ws[((size_t)ks * BB + g) * NN + j] = v;
}

// Combine: tot = ws[0][b][j] * ws[1][b][j]; 4x4 mix + sampling epilogue.
// 32768 threads, fully coalesced over j.
__global__ __launch_bounds__(256) void epi_combine(
    const float* __restrict__ state,    // [B,4,N]
    const float* __restrict__ psMatrix, // [4,4]
    const float* __restrict__ U,        // [N]
    const double* __restrict__ ws,      // [KS,BB,NN]
    float* __restrict__ out)            // [B,4,N]
{
    const int p = blockIdx.x * 256 + threadIdx.x;   // 0 .. BB*NN-1
    const int b = p >> 12;              // NN = 4096 = 2^12
    const int j = p & (NN - 1);

    const double tot = ws[(size_t)b * NN + j] * ws[((size_t)BB * NN) + (size_t)b * NN + j];
    const double ps1 = 1.0 - tot;

    // expand_psMatrix in f64
    double pm[4][4];
    #pragma unroll
    for (int r = 0; r < 4; ++r) {
        double s = 0.0;
        #pragma unroll
        for (int q = 0; q < 4; ++q) {
            pm[r][q] = (double)psMatrix[r * 4 + q];
            s += pm[r][q];
        }
        pm[r][r] += (1.0 - s);
    }

    double st[4];
    #pragma unroll
    for (int r = 0; r < 4; ++r)
        st[r] = (double)state[(size_t)b * 4 * NN + r * NN + j];

    const double S = st[0];
    const double ps10[4] = {1.0 - ps1, ps1, 0.0, 0.0};

    double P[4];
    #pragma unroll
    for (int i = 0; i < 4; ++i) {
        double acc = S * ps10[i];
        #pragma unroll
        for (int r = 1; r < 4; ++r)
            acc += pm[r][i] * st[r];
        P[i] = acc;
    }

    double u = (double)U[j];
    #pragma unroll
    for (int i = 0; i < 4; ++i) {
        u -= P[i];
        const double s = (u < 0.0) ? 1.0 : 0.0;
        out[(size_t)b * 4 * NN + i * NN + j] = (float)s;
        u += s;
    }
}

// ---------- Fallback (verbatim round-6 kernel, used only if ws too small) ----------
__global__ __launch_bounds__(256, 4) void epi_fallback(
    const float* __restrict__ state, const float* __restrict__ ISNet,
    const float* __restrict__ psMatrix, const float* __restrict__ U,
    float* __restrict__ out)
{
    const int j0 = blockIdx.x * JT;
    const int tid = threadIdx.x;
    const int wave = tid >> 6, lane = tid & 63;
    const int b0 = wave * 2;
    const float p01 = psMatrix[1];
    float cf[JT][2]; double prod[JT][2];
    #pragma unroll
    for (int jj = 0; jj < JT; ++jj)
        #pragma unroll
        for (int bi = 0; bi < 2; ++bi) {
            cf[jj][bi] = state[(size_t)(b0 + bi) * 4 * NN + (j0 + jj)] * p01;
            prod[jj][bi] = 1.0;
        }
    const float4* __restrict__ w0 = (const float4*)(ISNet + (size_t)(j0 + 0) * NN);
    const float4* __restrict__ w1 = (const float4*)(ISNet + (size_t)(j0 + 1) * NN);
    const float4* __restrict__ w2 = (const float4*)(ISNet + (size_t)(j0 + 2) * NN);
    const float4* __restrict__ w3 = (const float4*)(ISNet + (size_t)(j0 + 3) * NN);
    const float4* __restrict__ i0 = (const float4*)(state + ((size_t)(b0 + 0) * 4 + 2) * NN);
    const float4* __restrict__ i1 = (const float4*)(state + ((size_t)(b0 + 1) * 4 + 2) * NN);
    float4 wA[JT], wB[JT], wC[JT], ia[2], ib[2];
#define LW(BUF, IDX) do { const int _x = lane + (IDX) * 64; \
        BUF[0] = w0[_x]; BUF[1] = w1[_x]; BUF[2] = w2[_x]; BUF[3] = w3[_x]; } while (0)
#define LI(BUF, IDX) do { const int _x = lane + (IDX) * 64; \
        BUF[0] = i0[_x]; BUF[1] = i1[_x]; } while (0)
    auto compute = [&](const float4 (&W)[JT], const float4 (&I)[2]) {
        #pragma unroll
        for (int jj = 0; jj < JT; ++jj) {
            const float2 w01 = make_float2(W[jj].x, W[jj].y);
            const float2 w23 = make_float2(W[jj].z, W[jj].w);
            #pragma unroll
            for (int bi = 0; bi < 2; ++bi) {
                const float4& I4 = bi ? I[1] : I[0];
                const float2 c2 = make_float2(cf[jj][bi], cf[jj][bi]);
                const float2 z01 = pk_mul(pk_mul(c2, w01), make_float2(I4.x, I4.y));
                const float2 z23 = pk_mul(pk_mul(c2, w23), make_float2(I4.z, I4.w));
                const float2 q2 = pk_fnma(z01, z23, pk_add(z01, z23));
                const float q = fmaf(-q2.x, q2.y, q2.x + q2.y);
                prod[jj][bi] = fma(-(double)q, prod[jj][bi], prod[jj][bi]);
            }
        }
    };
#define STEP(W, I, K) do { compute(W, I); \
        if ((K) + 3 < 16) LW(W, (K) + 3); if ((K) + 2 < 16) LI(I, (K) + 2); } while (0)
    LW(wA, 0); LI(ia, 0); LW(wB, 1); LI(ib, 1); LW(wC, 2);
    STEP(wA, ia, 0);  STEP(wB, ib, 1);  STEP(wC, ia, 2);  STEP(wA, ib, 3);
    STEP(wB, ia, 4);  STEP(wC, ib, 5);  STEP(wA, ia, 6);  STEP(wB, ib, 7);
    STEP(wC, ia, 8);  STEP(wA, ib, 9);  STEP(wB, ia, 10); STEP(wC, ib, 11);
    STEP(wA, ia, 12); STEP(wB, ib, 13); STEP(wC, ia, 14); STEP(wA, ib, 15);
#undef STEP
#undef LW
#undef LI
    #pragma unroll
    for (int off = 32; off >= 8; off >>= 1)
        #pragma unroll
        for (int jj = 0; jj < JT; ++jj)
            #pragma unroll
            for (int bi = 0; bi < 2; ++bi)
                prod[jj][bi] *= __shfl_xor(prod[jj][bi], off, 64);
    const int g = lane >> 3;
    double v = prod[0][0];
    v = (g == 1) ? prod[0][1] : v; v = (g == 2) ? prod[1][0] : v;
    v = (g == 3) ? prod[1][1] : v; v = (g == 4) ? prod[2][0] : v;
    v = (g == 5) ? prod[2][1] : v; v = (g == 6) ? prod[3][0] : v;
    v = (g == 7) ? prod[3][1] : v;
    v *= __shfl_down(v, 4, 64); v *= __shfl_down(v, 2, 64); v *= __shfl_down(v, 1, 64);
    __shared__ double red[JT][BB];
    if ((lane & 7) == 0) red[g >> 1][b0 + (g & 1)] = v;
    __syncthreads();
    if (tid < JT * BB) {
        const int jj = tid >> 3, b = tid & 7;
        const int j = j0 + jj;
        const double ps1 = 1.0 - red[jj][b];
        double pm[4][4];
        #pragma unroll
        for (int r = 0; r < 4; ++r) {
            double s = 0.0;
            #pragma unroll
            for (int q = 0; q < 4; ++q) { pm[r][q] = (double)psMatrix[r * 4 + q]; s += pm[r][q]; }
            pm[r][r] += (1.0 - s);
        }
        double st[4];
        #pragma unroll
        for (int r = 0; r < 4; ++r) st[r] = (double)state[(size_t)b * 4 * NN + r * NN + j];
        const double S = st[0];
        const double ps10[4] = {1.0 - ps1, ps1, 0.0, 0.0};
        double P[4];
        #pragma unroll
        for (int i = 0; i < 4; ++i) {
            double acc = S * ps10[i];
            #pragma unroll
            for (int r = 1; r < 4; ++r) acc += pm[r][i] * st[r];
            P[i] = acc;
        }
        double u = (double)U[j];
        #pragma unroll
        for (int i = 0; i < 4; ++i) {
            u -= P[i];
            const double s = (u < 0.0) ? 1.0 : 0.0;
            out[(size_t)b * 4 * NN + i * NN + j] = (float)s;
            u += s;
        }
    }
}

extern "C" void kernel_launch(void* const* d_in, const int* in_sizes, int n_in,
                              void* d_out, int out_size, void* d_ws, size_t ws_size,
                              hipStream_t stream) {
    const float* state    = (const float*)d_in[0];  // [8,4,4096]
    const float* ISNet    = (const float*)d_in[1];  // [4096,4096]
    const float* psMatrix = (const float*)d_in[2];  // [4,4]
    const float* U        = (const float*)d_in[3];  // [4096]
    float* out            = (float*)d_out;          // [8,4,4096]

    const size_t need = (size_t)KS * BB * NN * sizeof(double);  // 512 KB
    if (ws_size >= need) {
        double* ws = (double*)d_ws;
        epi_partial<<<(NN / JT) * KS, 256, 0, stream>>>(state, ISNet, psMatrix, ws);
        epi_combine<<<(BB * NN) / 256, 256, 0, stream>>>(state, psMatrix, U, ws, out);
    } else {
        epi_fallback<<<NN / JT, 256, 0, stream>>>(state, ISNet, psMatrix, U, out);
    }
}